// Round 8
// baseline (296.838 us; speedup 1.0000x reference)
//
#include <hip/hip_runtime.h>

#define DIN 128

// ---------------------------------------------------------------------------
// out = round(clip( A^2 (X w1f) + c1*(A 1) + c0 , 0, 10)),  A = D^-1/2 (W+I) D^-1/2
// w2f = W2@fcw, w1f = W1@w2f, c1 = b1·w2f, c0 = b2·fcw + fcb.
//
// Scatter side reduced to ONE scattered op per edge (the ~20G scattered-ops/s
// fabric ceiling is the structural floor): atomicExch pushes edge i onto a
// per-dst linked list; the payload {next, src, ew} is written COALESCED at
// ed[i]. Gather phases walk the chains (scattered L2/L3 *reads* are cheap).
//   K1: fold head weights -> w1f, c0, c1; head[] = -1
//   K2: per-edge list-push (+ gemv q = X@w1f in the same grid)
//   K3: walk: deg -> dis; pk1 = {q, dis}; pk2 = {c1 + dis^2 q, dis}
//   K4: walk: pk2.x += sum nm * q[s]          (pk1[s] = one 16B load)
//   K5: walk: u = c0 + dis^2 t + sum nm*t[s]; out = round(clip(u,0,10))
// f64 node values; f32 norm/deg math matches the reference.
// ---------------------------------------------------------------------------

__global__ void precompute_kernel(const float* __restrict__ W1, const float* __restrict__ b1,
                                  const float* __restrict__ W2, const float* __restrict__ b2,
                                  const float* __restrict__ fcw, const float* __restrict__ fcb,
                                  double* __restrict__ w1f, double* __restrict__ cvals,
                                  int* __restrict__ head, int n) {
    const int t = threadIdx.x;
    if (blockIdx.x > 0) {
        int i = (blockIdx.x - 1) * 256 + t;
        if (i < n) head[i] = -1;
        return;
    }
    __shared__ double sw2f[64];
    if (t < 64) {
        double s = 0.0;
        for (int j = 0; j < 64; j++) s += (double)W2[t * 64 + j] * (double)fcw[j];
        sw2f[t] = s;
    }
    __syncthreads();
    if (t < 128) {
        double s = 0.0;
        for (int j = 0; j < 64; j++) s += (double)W1[t * 64 + j] * sw2f[j];
        w1f[t] = s;
    }
    if (t == 128) {
        double c1 = 0.0, c0 = (double)fcb[0];
        for (int j = 0; j < 64; j++) {
            c1 += (double)b1[j] * sw2f[j];
            c0 += (double)b2[j] * (double)fcw[j];
        }
        cvals[0] = c0;
        cvals[1] = c1;
    }
}

// blocks [0,eblk): per-edge list push (1 scattered atomic + 1 coalesced 16B
// write); blocks [eblk,..): gemv q = X @ w1f, one row per wave
__global__ __launch_bounds__(256) void scatter_gemv_kernel(
        const int* __restrict__ src, const int* __restrict__ dst,
        const float* __restrict__ ew, const float* __restrict__ X,
        const double* __restrict__ w1f, int* __restrict__ head,
        uint4* __restrict__ ed, double* __restrict__ q,
        int n, int e, int eblk) {
    const int blk = blockIdx.x;
    const int t = threadIdx.x;
    if (blk < eblk) {
        int i = blk * 256 + t;
        if (i < e) {
            int d = dst[i];
            int old = atomicExch(&head[d], i);   // the one scattered op
            ed[i] = uint4{(unsigned)old, (unsigned)src[i], __float_as_uint(ew[i]), 0u};
        }
        return;
    }
    long g = (long)(blk - eblk) * 256 + t;
    int row = (int)(g >> 6);
    int lane = (int)(g & 63);
    if (row >= n) return;
    float2 x = *(const float2*)(X + (long)row * DIN + 2 * lane);  // 512B/wave coalesced
    double v = (double)x.x * w1f[2 * lane] + (double)x.y * w1f[2 * lane + 1];
#pragma unroll
    for (int off = 32; off > 0; off >>= 1) v += __shfl_down(v, off, 64);
    if (lane == 0) q[row] = v;
}

// thread-per-node chain walk: deg = 1 + sum(ew) -> dis; build pk1/pk2
__global__ __launch_bounds__(256) void walk_deg_kernel(
        const int* __restrict__ head, const uint4* __restrict__ ed,
        const double* __restrict__ q, const double* __restrict__ cvals,
        double2* __restrict__ pk1, double2* __restrict__ pk2, int n) {
    int i = blockIdx.x * 256 + threadIdx.x;
    if (i >= n) return;
    int cur = head[i];
    float wsum = 0.0f;
    while (cur >= 0) {
        uint4 v = ed[cur];           // one 16B read per hop
        wsum += __uint_as_float(v.z);
        cur = (int)v.x;
    }
    float d = 1.0f + wsum;  // self-loop weight 1
    float di = (d > 0.0f) ? (1.0f / sqrtf(fmaxf(d, 1e-12f))) : 0.0f;
    double qv = q[i];
    pk1[i] = double2{qv, (double)di};
    pk2[i] = double2{cvals[1] + (double)(di * di) * qv, (double)di};
}

// thread-per-node chain walk: pk2[i].x += sum nm * q[s]
__global__ __launch_bounds__(256) void walk_spmv1_kernel(
        const int* __restrict__ head, const uint4* __restrict__ ed,
        const double2* __restrict__ pk1, double2* __restrict__ pk2, int n) {
    int i = blockIdx.x * 256 + threadIdx.x;
    if (i >= n) return;
    double2 me = pk2[i];
    float di = (float)me.y;
    double acc = me.x;
    int cur = head[i];
    while (cur >= 0) {
        uint4 v = ed[cur];
        double2 a = pk1[v.y];        // one 16B random L2 load: {q, dis}
        float nm = (float)a.y * __uint_as_float(v.z) * di;  // fp32 norm
        acc += (double)nm * a.x;
        cur = (int)v.x;
    }
    pk2[i].x = acc;
}

// thread-per-node chain walk: u = c0 + dis^2 t + sum nm*t[s]; fused head
__global__ __launch_bounds__(256) void walk_spmv2_head_kernel(
        const int* __restrict__ head, const uint4* __restrict__ ed,
        const double2* __restrict__ pk2, const double* __restrict__ cvals,
        float* __restrict__ out, int n) {
    int i = blockIdx.x * 256 + threadIdx.x;
    if (i >= n) return;
    double2 me = pk2[i];
    float di = (float)me.y;
    double acc = cvals[0] + (double)(di * di) * me.x;
    int cur = head[i];
    while (cur >= 0) {
        uint4 v = ed[cur];
        double2 a = pk2[v.y];        // {t, dis}
        float nm = (float)a.y * __uint_as_float(v.z) * di;
        acc += (double)nm * a.x;
        cur = (int)v.x;
    }
    float o = (float)acc;
    o = fminf(fmaxf(o, 0.0f), 10.0f);
    out[i] = rintf(o);  // v_rndne_f32: half-to-even, matches jnp.round
}

extern "C" void kernel_launch(void* const* d_in, const int* in_sizes, int n_in,
                              void* d_out, int out_size, void* d_ws, size_t ws_size,
                              hipStream_t stream) {
    const float* x   = (const float*)d_in[0];  // [N, 128]
    const int*   eix = (const int*)d_in[1];    // [2, E]
    const float* ew  = (const float*)d_in[2];  // [E]
    const float* W1  = (const float*)d_in[3];  // [128, 64]
    const float* b1  = (const float*)d_in[4];  // [64]
    const float* W2  = (const float*)d_in[5];  // [64, 64]
    const float* b2  = (const float*)d_in[6];  // [64]
    const float* fcw = (const float*)d_in[7];  // [64]
    const float* fcb = (const float*)d_in[8];  // [1]
    float* out = (float*)d_out;                // [N]

    const int n = in_sizes[0] / DIN;
    const int e = in_sizes[2];
    const int* src = eix;
    const int* dst = eix + e;

    // workspace layout (8-byte units, 512B-aligned regions); ~34 MB
    auto al = [](size_t v) { return (v + 63) & ~(size_t)63; };
    double* ws = (double*)d_ws;
    size_t o = 0;
    double*  w1f   = ws + o; o += al(DIN);
    double*  cvals = ws + o; o += al(2);
    double*  q     = ws + o; o += al((size_t)n);
    double2* pk1   = (double2*)(ws + o); o += al((size_t)n * 2);
    double2* pk2   = (double2*)(ws + o); o += al((size_t)n * 2);
    int*     head  = (int*)(ws + o);     o += al(((size_t)n + 1) / 2);
    uint4*   ed    = (uint4*)(ws + o);   // e * 16B = 25.6 MB

    const int nblk = (n + 255) / 256;
    const int eblk = (e + 255) / 256;
    const int gemvblk = (n + 3) / 4;   // 4 rows (waves) per block

    precompute_kernel<<<1 + nblk, 256, 0, stream>>>(W1, b1, W2, b2, fcw, fcb,
                                                    w1f, cvals, head, n);
    scatter_gemv_kernel<<<eblk + gemvblk, 256, 0, stream>>>(src, dst, ew, x, w1f,
                                                            head, ed, q, n, e, eblk);
    walk_deg_kernel<<<nblk, 256, 0, stream>>>(head, ed, q, cvals, pk1, pk2, n);
    walk_spmv1_kernel<<<nblk, 256, 0, stream>>>(head, ed, pk1, pk2, n);
    walk_spmv2_head_kernel<<<nblk, 256, 0, stream>>>(head, ed, pk2, cvals, out, n);
}